// Round 4
// baseline (523.638 us; speedup 1.0000x reference)
//
#include <hip/hip_runtime.h>
#include <cstdint>
#include <cstddef>

// ---------------------------------------------------------------------------
// TransformerLayer: hidden,k,v = f(x, qw,qb, kw,kb, vw,vb, w1,b1, w2,b2)
// S=4096, D_MODEL=2048, D_INT=512.  bf16 MFMA GEMMs, fp32 accumulate.
// Round 4: 256^2 8-phase GEMM (T2 swizzle + T3/T4 counted vmcnt + T5 setprio)
// for the big GEMMs; QK stays on the 2-phase 128^2 kernel.
// ---------------------------------------------------------------------------

typedef __attribute__((ext_vector_type(8))) short short8;   // 8 x bf16 bits
typedef __attribute__((ext_vector_type(4))) float f32x4;    // MFMA accum

typedef __attribute__((address_space(3))) void lds_void;
typedef __attribute__((address_space(1))) void g_void;

#define SEQ    4096
#define DMODEL 2048
#define DINT   512

#define MEMF() asm volatile("" ::: "memory")
#define BARRIER() do { MEMF(); __builtin_amdgcn_s_barrier(); MEMF(); } while (0)

// fp32 -> bf16 bits, round-to-nearest-even
__device__ __forceinline__ unsigned short f2bf(float f) {
  union { float f; unsigned int u; } a;
  a.f = f;
  unsigned int u = a.u;
  u += 0x7fffu + ((u >> 16) & 1u);
  return (unsigned short)(u >> 16);
}

// ---------------------------------------------------------------------------
// cast: fp32 -> bf16 (4 elems / thread)
// ---------------------------------------------------------------------------
__global__ __launch_bounds__(256) void cast_bf16_kernel(
    const float* __restrict__ in, unsigned short* __restrict__ out, int n4) {
  int i = blockIdx.x * 256 + threadIdx.x;
  if (i >= n4) return;
  float4 v = ((const float4*)in)[i];
  ushort4 o;
  o.x = f2bf(v.x); o.y = f2bf(v.y); o.z = f2bf(v.z); o.w = f2bf(v.w);
  ((ushort4*)out)[i] = o;
}

// ---------------------------------------------------------------------------
// bf16 transpose: out[C][R] = in[R][C].  64x64 LDS tile.
// ---------------------------------------------------------------------------
__global__ __launch_bounds__(256) void transpose_bf16_kernel(
    const unsigned short* __restrict__ in, unsigned short* __restrict__ out,
    int R, int C) {
  __shared__ unsigned short tile[64][65];
  const int tx = threadIdx.x & 63;
  const int ty = threadIdx.x >> 6;          // 0..3
  const int r0 = blockIdx.x * 64;
  const int c0 = blockIdx.y * 64;
#pragma unroll
  for (int i = 0; i < 64; i += 4)
    tile[ty + i][tx] = in[(size_t)(r0 + ty + i) * C + c0 + tx];
  __syncthreads();
#pragma unroll
  for (int i = 0; i < 64; i += 4)
    out[(size_t)(c0 + ty + i) * R + r0 + tx] = tile[tx][ty + i];
}

// ---------------------------------------------------------------------------
// 2-phase 128^2 GEMM (round-3 kernel), kept for the QK fused GEMM (N=1024).
// ---------------------------------------------------------------------------
#define BM 128
#define BN 128
#define BK 64

__global__ __launch_bounds__(256)
void gemm_bt_kernel(const unsigned short* __restrict__ A,
                    const unsigned short* __restrict__ B,
                    int M, int N, int K, int split,
                    const float* __restrict__ biasA,
                    const float* __restrict__ biasB,
                    const float* __restrict__ resid,
                    float scale, int relu,
                    float* __restrict__ outFA,
                    unsigned short* __restrict__ outBA,
                    float* __restrict__ outFB,
                    unsigned short* __restrict__ outBB)
{
  __shared__ __align__(16) unsigned short As[2][BM][BK];
  __shared__ __align__(16) unsigned short Bs[2][BN][BK];

  const int tid  = threadIdx.x;
  const int lane = tid & 63;
  const int wave = tid >> 6;
  const int wr   = wave >> 1;
  const int wc   = wave & 1;
  const int brow = blockIdx.x * BM;
  const int bcol = blockIdx.y * BN;
  const int lr   = lane & 15;
  const int kg   = lane >> 4;

  const int srow  = tid >> 3;
  const int scol  = (tid & 7) * 8;
  const int wbase = wave * 8;
  const unsigned short* Ab = A + (size_t)(brow + srow) * K + scol;
  const unsigned short* Bb = B + (size_t)(bcol + srow) * K + scol;

  f32x4 acc[4][4];
#pragma unroll
  for (int i = 0; i < 4; i++)
#pragma unroll
    for (int j = 0; j < 4; j++) acc[i][j] = (f32x4){0.f, 0.f, 0.f, 0.f};

  auto stage = [&](int d, int k0) {
#pragma unroll
    for (int j = 0; j < 4; ++j) {
      __builtin_amdgcn_global_load_lds((const g_void*)(Ab + (size_t)(j * 32) * K + k0),
                                       (lds_void*)&As[d][j * 32 + wbase][0], 16, 0, 0);
      __builtin_amdgcn_global_load_lds((const g_void*)(Bb + (size_t)(j * 32) * K + k0),
                                       (lds_void*)&Bs[d][j * 32 + wbase][0], 16, 0, 0);
    }
  };

  auto compute = [&](int d) {
    short8 aF[4][2], bF[4][2];
#pragma unroll
    for (int mi = 0; mi < 4; ++mi)
#pragma unroll
      for (int ks = 0; ks < 2; ++ks)
        aF[mi][ks] = *(const short8*)&As[d][wr * 64 + mi * 16 + lr][ks * 32 + kg * 8];
#pragma unroll
    for (int ni = 0; ni < 4; ++ni)
#pragma unroll
      for (int ks = 0; ks < 2; ++ks)
        bF[ni][ks] = *(const short8*)&Bs[d][wc * 64 + ni * 16 + lr][ks * 32 + kg * 8];
#pragma unroll
    for (int ks = 0; ks < 2; ++ks)
#pragma unroll
      for (int mi = 0; mi < 4; ++mi)
#pragma unroll
        for (int ni = 0; ni < 4; ++ni)
          acc[mi][ni] = __builtin_amdgcn_mfma_f32_16x16x32_bf16(
              aF[mi][ks], bF[ni][ks], acc[mi][ni], 0, 0, 0);
  };

  stage(0, 0);
  __syncthreads();
  int c = 0;
  const int NT = K >> 6;
  for (int t = 0; t < NT; ++t) {
    if (t + 1 < NT) stage(c ^ 1, (t + 1) << 6);
    compute(c);
    __syncthreads();
    c ^= 1;
  }

  const int wB = N - split;
#pragma unroll
  for (int mi = 0; mi < 4; mi++) {
#pragma unroll
    for (int ni = 0; ni < 4; ni++) {
#pragma unroll
      for (int r = 0; r < 4; r++) {
        const int row = brow + wr * 64 + mi * 16 + kg * 4 + r;
        const int col = bcol + wc * 64 + ni * 16 + lr;
        float v = acc[mi][ni][r] * scale;
        if (col < split) {
          if (biasA) v += biasA[col];
          if (resid) v += resid[(size_t)row * N + col];
          if (relu)  v = fmaxf(v, 0.0f);
          if (outFA) outFA[(size_t)row * split + col] = v;
          if (outBA) outBA[(size_t)row * split + col] = f2bf(v);
        } else {
          const int c2 = col - split;
          if (biasB) v += biasB[c2];
          if (outFB) outFB[(size_t)row * wB + c2] = v;
          if (outBB) outBB[(size_t)row * wB + c2] = f2bf(v);
        }
      }
    }
  }
}

// ---------------------------------------------------------------------------
// 256^2 8-phase GEMM:  C[M,N] = scale*(A[M,K] @ B[N,K]^T) (+bias)(+resid)(relu)
// 512 thr = 8 waves (2M x 4N), per-wave 128x64 output (8x4 frags 16x16x32),
// BK=64.  LDS [op][dbuf][half][128][64] bf16 = 128 KiB.
// Per K-tile, 4 phases: {ds_read frags | stage 1 half-tile | bar | 16 MFMA
// (setprio) | bar}; counted vmcnt(4) ONCE per K-tile (never 0); raw
// s_barrier (no implicit drain).  T2 swizzle kelem ^= (row&7)<<3 applied as
// inverse-swizzled GLOBAL source + swizzled ds_read (linear gload dest).
// Schedule safety: A(t+1)->buf^1 (unread during t, staged p0/p1);
// B(t+2)->buf, B-halves fully consumed by end of p1 (staged p2/p3).
// Boundary invariant: 4 loads in flight; vmcnt(4) drains tile t+1 resident.
// ---------------------------------------------------------------------------
__global__ __launch_bounds__(512, 2)
void gemm256_kernel(const unsigned short* __restrict__ A,
                    const unsigned short* __restrict__ B,
                    int M, int N, int K,
                    const float* __restrict__ bias,
                    const float* __restrict__ resid,
                    float scale, int relu,
                    float* __restrict__ outF,
                    unsigned short* __restrict__ outB)
{
  __shared__ __align__(16) unsigned short lds[2][2][2][128][64];  // 128 KiB

  const int tid  = threadIdx.x;
  const int lane = tid & 63;
  const int wave = tid >> 6;     // 0..7
  const int wm   = wave >> 2;    // 0..1  (M-half of tile)
  const int wn   = wave & 3;     // 0..3  (64-col strip)
  const int lr   = lane & 15;
  const int kg   = lane >> 4;
  const int brow = blockIdx.x * 256;
  const int bcol = blockIdx.y * 256;

  // staging: thread t covers row (t>>3) of a 64-row chunk, 16B at swizzled k.
  const int srow = tid >> 3;                              // 0..63
  const int ssw  = ((tid & 7) * 8) ^ ((srow & 7) << 3);   // pre-swizzled k-elem
  const unsigned short* Asrc = A + (size_t)(brow + srow) * K + ssw;
  const unsigned short* Bsrc = B + (size_t)(bcol + srow) * K + ssw;

  char* lbase = (char*)&lds[0][0][0][0][0];
  const int woff = wave * 1024;              // wave-uniform dest offset

  f32x4 acc[8][4];
#pragma unroll
  for (int i = 0; i < 8; ++i)
#pragma unroll
    for (int j = 0; j < 4; ++j) acc[i][j] = (f32x4){0.f, 0.f, 0.f, 0.f};

  const int NT = K >> 6;

  // stage one half-tile (128 rows x 64 k) = 2 block-wide global_load_lds
  auto STAGE = [&](int op, int dbuf, int half, int tile) {
    const unsigned short* src = op ? Bsrc : Asrc;
    char* d = lbase + op * 65536 + dbuf * 32768 + half * 16384 + woff;
#pragma unroll
    for (int j = 0; j < 2; ++j)
      __builtin_amdgcn_global_load_lds(
          (const g_void*)(src + (size_t)(half * 128 + j * 64) * K + tile * 64),
          (lds_void*)(d + j * 8192), 16, 0, 0);
  };

  // fragment reads (swizzled)
  auto LDA = [&](short8* a, int dbuf, int mh, int ks) {
    const char* reg = lbase + dbuf * 32768 + wm * 16384;
    const int ke = (ks * 32 + kg * 8) ^ ((lr & 7) << 3);
#pragma unroll
    for (int i = 0; i < 4; ++i) {
      const int row = (mh * 4 + i) * 16 + lr;
      a[i] = *(const short8*)(reg + row * 128 + ke * 2);
    }
  };
  auto LDB = [&](short8* b, int dbuf, int ks) {
    const char* reg = lbase + 65536 + dbuf * 32768 + (wn >> 1) * 16384;
    const int ke = (ks * 32 + kg * 8) ^ ((lr & 7) << 3);
#pragma unroll
    for (int n = 0; n < 4; ++n) {
      const int row = (wn & 1) * 64 + n * 16 + lr;
      b[n] = *(const short8*)(reg + row * 128 + ke * 2);
    }
  };

  auto MM = [&](int mh, short8* a, short8* b) {
    __builtin_amdgcn_s_setprio(1);
#pragma unroll
    for (int i = 0; i < 4; ++i)
#pragma unroll
      for (int n = 0; n < 4; ++n)
        acc[mh * 4 + i][n] = __builtin_amdgcn_mfma_f32_16x16x32_bf16(
            a[i], b[n], acc[mh * 4 + i][n], 0, 0, 0);
    __builtin_amdgcn_s_setprio(0);
  };

  // prologue: tile 0 (both ops) + B halves of tile 1
  STAGE(0, 0, 0, 0); STAGE(0, 0, 1, 0);
  STAGE(1, 0, 0, 0); STAGE(1, 0, 1, 0);
  if (NT > 1) {
    STAGE(1, 1, 0, 1); STAGE(1, 1, 1, 1);
    asm volatile("s_waitcnt vmcnt(4)" ::: "memory");
  } else {
    asm volatile("s_waitcnt vmcnt(0)" ::: "memory");
  }
  BARRIER();

  short8 aT[4], bF0[4], bF1[4];
  for (int t = 0; t < NT; ++t) {
    const int buf = t & 1;
    const int tn1 = (t + 1 < NT) ? t + 1 : NT - 1;   // clamped: count-uniform
    const int tn2 = (t + 2 < NT) ? t + 2 : NT - 1;

    // phase 0: a(mh0,ks0) + b(ks0) [8 reads]; stage A-half0(t+1) -> buf^1
    LDA(aT, buf, 0, 0); LDB(bF0, buf, 0);
    STAGE(0, buf ^ 1, 0, tn1);
    BARRIER();
    MM(0, aT, bF0);
    BARRIER();

    // phase 1: a(mh0,ks1) + b(ks1) [8 reads]; stage A-half1(t+1) -> buf^1
    LDA(aT, buf, 0, 1); LDB(bF1, buf, 1);
    STAGE(0, buf ^ 1, 1, tn1);
    BARRIER();
    MM(0, aT, bF1);
    BARRIER();

    // phase 2: a(mh1,ks0) [4 reads]; stage B-half0(t+2) -> buf
    LDA(aT, buf, 1, 0);
    STAGE(1, buf, 0, tn2);
    BARRIER();
    MM(1, aT, bF0);
    BARRIER();

    // phase 3: a(mh1,ks1) [4 reads]; stage B-half1(t+2) -> buf
    LDA(aT, buf, 1, 1);
    STAGE(1, buf, 1, tn2);
    BARRIER();
    MM(1, aT, bF1);
    asm volatile("s_waitcnt vmcnt(4)" ::: "memory");   // tile t+1 resident
    BARRIER();
  }

  // drain in-flight LDS-DMA before workgroup can retire
  asm volatile("s_waitcnt vmcnt(0)" ::: "memory");

  // epilogue: D row = kg*4+r, col = lr within each 16x16 frag
#pragma unroll
  for (int mi = 0; mi < 8; ++mi) {
#pragma unroll
    for (int ni = 0; ni < 4; ++ni) {
#pragma unroll
      for (int r = 0; r < 4; ++r) {
        const int row = brow + wm * 128 + mi * 16 + kg * 4 + r;
        const int col = bcol + wn * 64 + ni * 16 + lr;
        float v = acc[mi][ni][r] * scale;
        if (bias)  v += bias[col];
        if (resid) v += resid[(size_t)row * N + col];
        if (relu)  v = fmaxf(v, 0.0f);
        if (outF)  outF[(size_t)row * N + col] = v;
        if (outB)  outB[(size_t)row * N + col] = f2bf(v);
      }
    }
  }
}

// ---------------------------------------------------------------------------
// row softmax: one block per row of [SEQ, SEQ] fp32 scores -> bf16 probs
// ---------------------------------------------------------------------------
__global__ __launch_bounds__(256) void softmax_kernel(
    const float* __restrict__ Sc, unsigned short* __restrict__ P) {
  __shared__ float buf[SEQ];
  __shared__ float redm[4];
  __shared__ float reds[4];
  const int tid = threadIdx.x;
  const int row = blockIdx.x;
  const float* src = Sc + (size_t)row * SEQ;

  float lmax = -3.0e38f;
  for (int i = tid * 4; i < SEQ; i += 1024) {
    float4 v = *(const float4*)(src + i);
    buf[i] = v.x; buf[i + 1] = v.y; buf[i + 2] = v.z; buf[i + 3] = v.w;
    lmax = fmaxf(lmax, fmaxf(fmaxf(v.x, v.y), fmaxf(v.z, v.w)));
  }
#pragma unroll
  for (int off = 32; off > 0; off >>= 1)
    lmax = fmaxf(lmax, __shfl_xor(lmax, off, 64));
  if ((tid & 63) == 0) redm[tid >> 6] = lmax;
  __syncthreads();
  const float m = fmaxf(fmaxf(redm[0], redm[1]), fmaxf(redm[2], redm[3]));

  float lsum = 0.0f;
  for (int i = tid; i < SEQ; i += 256) {
    float e = __expf(buf[i] - m);
    buf[i] = e;
    lsum += e;
  }
#pragma unroll
  for (int off = 32; off > 0; off >>= 1)
    lsum += __shfl_xor(lsum, off, 64);
  if ((tid & 63) == 0) reds[tid >> 6] = lsum;
  __syncthreads();
  const float inv = 1.0f / (reds[0] + reds[1] + reds[2] + reds[3]);

  unsigned short* dst = P + (size_t)row * SEQ;
  for (int i = tid; i < SEQ; i += 256) dst[i] = f2bf(buf[i] * inv);
}

// ---------------------------------------------------------------------------
// launch
// ---------------------------------------------------------------------------
extern "C" void kernel_launch(void* const* d_in, const int* in_sizes, int n_in,
                              void* d_out, int out_size, void* d_ws, size_t ws_size,
                              hipStream_t stream) {
  const float* x  = (const float*)d_in[0];
  const float* qw = (const float*)d_in[1];
  const float* qb = (const float*)d_in[2];
  const float* kw = (const float*)d_in[3];
  const float* kb = (const float*)d_in[4];
  const float* vw = (const float*)d_in[5];
  const float* vb = (const float*)d_in[6];
  const float* w1 = (const float*)d_in[7];
  const float* b1 = (const float*)d_in[8];
  const float* w2 = (const float*)d_in[9];
  const float* b2 = (const float*)d_in[10];
  float* out = (float*)d_out;   // [hidden(8388608) | k(2097152) | v(8388608)]
  char* ws = (char*)d_ws;

  const size_t MB = 1048576;
  unsigned short* Xb   = (unsigned short*)(ws + 0 * MB);
  unsigned short* VWb  = (unsigned short*)(ws + 16 * MB);
  unsigned short* QKWb = (unsigned short*)(ws + 24 * MB);
  unsigned short* Pb   = (unsigned short*)(ws + 0 * MB);     // overlays Xb/VWb/QKWb
  unsigned short* W1b  = (unsigned short*)(ws + 32 * MB);
  unsigned short* W2b  = (unsigned short*)(ws + 40 * MB);
  unsigned short* Qb   = (unsigned short*)(ws + 48 * MB);
  unsigned short* Kb   = (unsigned short*)(ws + 52 * MB);
  unsigned short* Vb   = (unsigned short*)(ws + 56 * MB);
  unsigned short* VTb  = (unsigned short*)(ws + 72 * MB);
  float*          Sc   = (float*)(ws + 88 * MB);
  float*          XR   = (float*)(ws + 88 * MB);             // overlays dead Sc
  unsigned short* X1b  = (unsigned short*)(ws + 120 * MB);   // overlays dead Sc
  unsigned short* XRb  = (unsigned short*)(ws + 136 * MB);   // overlays dead Sc

  // casts to bf16 (QKWb = [qw ; kw] rows concatenated)
  cast_bf16_kernel<<<8192, 256, 0, stream>>>(x,  Xb,  2097152);
  cast_bf16_kernel<<<1024, 256, 0, stream>>>(qw, QKWb, 262144);
  cast_bf16_kernel<<<1024, 256, 0, stream>>>(kw, QKWb + 512 * 2048, 262144);
  cast_bf16_kernel<<<4096, 256, 0, stream>>>(vw, VWb, 1048576);
  cast_bf16_kernel<<<4096, 256, 0, stream>>>(w1, W1b, 1048576);
  cast_bf16_kernel<<<4096, 256, 0, stream>>>(w2, W2b, 1048576);

  // q,k = x @ [qw;kw]^T + [qb;kb]   (fused, split epilogue; 2-phase kernel)
  gemm_bt_kernel<<<dim3(32, 8), dim3(256), 0, stream>>>(
      Xb, QKWb, SEQ, 1024, DMODEL, 512, qb, kb, nullptr, 1.0f, 0,
      nullptr, Qb, out + 8388608, Kb);
  // v = x @ vw^T + vb   -> fp32 (out) + bf16
  gemm256_kernel<<<dim3(16, 8), dim3(512), 0, stream>>>(
      Xb, VWb, SEQ, DMODEL, DMODEL, vb, nullptr, 1.0f, 0,
      out + 10485760, Vb);
  // VTb = Vb^T  ([2048][4096])
  transpose_bf16_kernel<<<dim3(64, 32), dim3(256), 0, stream>>>(Vb, VTb, SEQ, DMODEL);
  // scores = (q @ k^T) / sqrt(512)  -> fp32
  gemm256_kernel<<<dim3(16, 16), dim3(512), 0, stream>>>(
      Qb, Kb, SEQ, SEQ, DINT, nullptr, nullptr,
      0.04419417382415922f, 0, Sc, nullptr);
  // P = softmax(scores)  -> bf16
  softmax_kernel<<<4096, dim3(256), 0, stream>>>(Sc, Pb);
  // x_residual = P @ V + x  -> fp32 + bf16
  gemm256_kernel<<<dim3(16, 8), dim3(512), 0, stream>>>(
      Pb, VTb, SEQ, DMODEL, SEQ, nullptr, x, 1.0f, 0, XR, XRb);
  // x1 = relu(x_residual @ w1^T + b1)  -> bf16
  gemm256_kernel<<<dim3(16, 8), dim3(512), 0, stream>>>(
      XRb, W1b, SEQ, DMODEL, DMODEL, b1, nullptr, 1.0f, 1, nullptr, X1b);
  // hidden = x1 @ w2^T + b2 + x_residual  -> fp32 (out)
  gemm256_kernel<<<dim3(16, 8), dim3(512), 0, stream>>>(
      X1b, W2b, SEQ, DMODEL, DMODEL, b2, XR, 1.0f, 0, out, nullptr);
}

// Round 5
// 396.943 us; speedup vs baseline: 1.3192x; 1.3192x over previous
//
#include <hip/hip_runtime.h>
#include <cstdint>
#include <cstddef>

// ---------------------------------------------------------------------------
// TransformerLayer: hidden,k,v = f(x, qw,qb, kw,kb, vw,vb, w1,b1, w2,b2)
// S=4096, D_MODEL=2048, D_INT=512.  bf16 MFMA GEMMs, fp32 accumulate.
// Round 5: deep-prefetch 8-phase GEMMs (m201 schedule, vmcnt(6), 2-tile
// flight) + 256x128 tile variant so N=2048 GEMMs fill all 256 CUs.
// ---------------------------------------------------------------------------

typedef __attribute__((ext_vector_type(8))) short short8;   // 8 x bf16 bits
typedef __attribute__((ext_vector_type(4))) float f32x4;    // MFMA accum

typedef __attribute__((address_space(3))) void lds_void;
typedef __attribute__((address_space(1))) void g_void;

#define SEQ    4096
#define DMODEL 2048
#define DINT   512

#define MEMF() asm volatile("" ::: "memory")
#define BARRIER() do { MEMF(); __builtin_amdgcn_s_barrier(); MEMF(); } while (0)
#define VMCNT6() asm volatile("s_waitcnt vmcnt(6)" ::: "memory")
#define VMCNT0() asm volatile("s_waitcnt vmcnt(0)" ::: "memory")

// fp32 -> bf16 bits, round-to-nearest-even
__device__ __forceinline__ unsigned short f2bf(float f) {
  union { float f; unsigned int u; } a;
  a.f = f;
  unsigned int u = a.u;
  u += 0x7fffu + ((u >> 16) & 1u);
  return (unsigned short)(u >> 16);
}

// ---------------------------------------------------------------------------
// cast: fp32 -> bf16 (4 elems / thread)
// ---------------------------------------------------------------------------
__global__ __launch_bounds__(256) void cast_bf16_kernel(
    const float* __restrict__ in, unsigned short* __restrict__ out, int n4) {
  int i = blockIdx.x * 256 + threadIdx.x;
  if (i >= n4) return;
  float4 v = ((const float4*)in)[i];
  ushort4 o;
  o.x = f2bf(v.x); o.y = f2bf(v.y); o.z = f2bf(v.z); o.w = f2bf(v.w);
  ((ushort4*)out)[i] = o;
}

// ---------------------------------------------------------------------------
// bf16 transpose: out[C][R] = in[R][C].  64x64 LDS tile.
// ---------------------------------------------------------------------------
__global__ __launch_bounds__(256) void transpose_bf16_kernel(
    const unsigned short* __restrict__ in, unsigned short* __restrict__ out,
    int R, int C) {
  __shared__ unsigned short tile[64][65];
  const int tx = threadIdx.x & 63;
  const int ty = threadIdx.x >> 6;
  const int r0 = blockIdx.x * 64;
  const int c0 = blockIdx.y * 64;
#pragma unroll
  for (int i = 0; i < 64; i += 4)
    tile[ty + i][tx] = in[(size_t)(r0 + ty + i) * C + c0 + tx];
  __syncthreads();
#pragma unroll
  for (int i = 0; i < 64; i += 4)
    out[(size_t)(c0 + ty + i) * R + r0 + tx] = tile[tx][ty + i];
}

// ---------------------------------------------------------------------------
// 2-phase 128^2 GEMM (round-3 kernel), kept for the QK fused GEMM (N=1024,
// grid 32x8 = 256 blocks).
// ---------------------------------------------------------------------------
#define BM 128
#define BN 128
#define BK 64

__global__ __launch_bounds__(256)
void gemm_bt_kernel(const unsigned short* __restrict__ A,
                    const unsigned short* __restrict__ B,
                    int M, int N, int K, int split,
                    const float* __restrict__ biasA,
                    const float* __restrict__ biasB,
                    const float* __restrict__ resid,
                    float scale, int relu,
                    float* __restrict__ outFA,
                    unsigned short* __restrict__ outBA,
                    float* __restrict__ outFB,
                    unsigned short* __restrict__ outBB)
{
  __shared__ __align__(16) unsigned short As[2][BM][BK];
  __shared__ __align__(16) unsigned short Bs[2][BN][BK];

  const int tid  = threadIdx.x;
  const int lane = tid & 63;
  const int wave = tid >> 6;
  const int wr   = wave >> 1;
  const int wc   = wave & 1;
  const int brow = blockIdx.x * BM;
  const int bcol = blockIdx.y * BN;
  const int lr   = lane & 15;
  const int kg   = lane >> 4;

  const int srow  = tid >> 3;
  const int scol  = (tid & 7) * 8;
  const int wbase = wave * 8;
  const unsigned short* Ab = A + (size_t)(brow + srow) * K + scol;
  const unsigned short* Bb = B + (size_t)(bcol + srow) * K + scol;

  f32x4 acc[4][4];
#pragma unroll
  for (int i = 0; i < 4; i++)
#pragma unroll
    for (int j = 0; j < 4; j++) acc[i][j] = (f32x4){0.f, 0.f, 0.f, 0.f};

  auto stage = [&](int d, int k0) {
#pragma unroll
    for (int j = 0; j < 4; ++j) {
      __builtin_amdgcn_global_load_lds((const g_void*)(Ab + (size_t)(j * 32) * K + k0),
                                       (lds_void*)&As[d][j * 32 + wbase][0], 16, 0, 0);
      __builtin_amdgcn_global_load_lds((const g_void*)(Bb + (size_t)(j * 32) * K + k0),
                                       (lds_void*)&Bs[d][j * 32 + wbase][0], 16, 0, 0);
    }
  };

  auto compute = [&](int d) {
    short8 aF[4][2], bF[4][2];
#pragma unroll
    for (int mi = 0; mi < 4; ++mi)
#pragma unroll
      for (int ks = 0; ks < 2; ++ks)
        aF[mi][ks] = *(const short8*)&As[d][wr * 64 + mi * 16 + lr][ks * 32 + kg * 8];
#pragma unroll
    for (int ni = 0; ni < 4; ++ni)
#pragma unroll
      for (int ks = 0; ks < 2; ++ks)
        bF[ni][ks] = *(const short8*)&Bs[d][wc * 64 + ni * 16 + lr][ks * 32 + kg * 8];
#pragma unroll
    for (int ks = 0; ks < 2; ++ks)
#pragma unroll
      for (int mi = 0; mi < 4; ++mi)
#pragma unroll
        for (int ni = 0; ni < 4; ++ni)
          acc[mi][ni] = __builtin_amdgcn_mfma_f32_16x16x32_bf16(
              aF[mi][ks], bF[ni][ks], acc[mi][ni], 0, 0, 0);
  };

  stage(0, 0);
  __syncthreads();
  int c = 0;
  const int NT = K >> 6;
  for (int t = 0; t < NT; ++t) {
    if (t + 1 < NT) stage(c ^ 1, (t + 1) << 6);
    compute(c);
    __syncthreads();
    c ^= 1;
  }

  const int wB = N - split;
#pragma unroll
  for (int mi = 0; mi < 4; mi++) {
#pragma unroll
    for (int ni = 0; ni < 4; ni++) {
#pragma unroll
      for (int r = 0; r < 4; r++) {
        const int row = brow + wr * 64 + mi * 16 + kg * 4 + r;
        const int col = bcol + wc * 64 + ni * 16 + lr;
        float v = acc[mi][ni][r] * scale;
        if (col < split) {
          if (biasA) v += biasA[col];
          if (resid) v += resid[(size_t)row * N + col];
          if (relu)  v = fmaxf(v, 0.0f);
          if (outFA) outFA[(size_t)row * split + col] = v;
          if (outBA) outBA[(size_t)row * split + col] = f2bf(v);
        } else {
          const int c2 = col - split;
          if (biasB) v += biasB[c2];
          if (outFB) outFB[(size_t)row * wB + c2] = v;
          if (outBB) outBB[(size_t)row * wB + c2] = f2bf(v);
        }
      }
    }
  }
}

// ---------------------------------------------------------------------------
// 256^2 8-phase GEMM, m201 deep schedule (scores GEMM: grid (16,16)).
// 8 waves 2Mx4N, per-wave 128x64.  LDS [op][dbuf][half][128][64] = 128 KiB.
// Staging at 64-row quarter granularity (1 glds = 512thr x 16B = 64 rows):
//   p0: A(t+1).h0q1, A(t+1).h1q1  (into buf^1; q1 regions freed at p3 of t-1)
//   p2: B(t+2).h0 (2) + A(t+2).h0q0 (into LIVE buf; regions freed at p1)
//   p3: B(t+2).h1 (2) + A(t+2).h1q0
// vmcnt(6) once per tile: drains the 8 oldest of <=14 outstanding = all of
// tile t+1 (verified by issue-order counting, steady state AND prologue).
// ---------------------------------------------------------------------------
__global__ __launch_bounds__(512, 2)
void gemm256_kernel(const unsigned short* __restrict__ A,
                    const unsigned short* __restrict__ B,
                    int M, int N, int K,
                    const float* __restrict__ bias,
                    const float* __restrict__ resid,
                    float scale, int relu,
                    float* __restrict__ outF,
                    unsigned short* __restrict__ outB)
{
  __shared__ __align__(16) unsigned short lds[2][2][2][128][64];  // 128 KiB

  const int tid  = threadIdx.x;
  const int lane = tid & 63;
  const int wave = tid >> 6;     // 0..7
  const int wm   = wave >> 2;    // 0..1  (128-row half)
  const int wn   = wave & 3;     // 0..3  (64-col strip)
  const int lr   = lane & 15;
  const int kg   = lane >> 4;
  const int brow = blockIdx.x * 256;
  const int bcol = blockIdx.y * 256;

  const int srow = tid >> 3;                              // 0..63
  const int ssw  = ((tid & 7) * 8) ^ ((srow & 7) << 3);   // pre-swizzled k
  const unsigned short* Asrc = A + (size_t)(brow + srow) * K + ssw;
  const unsigned short* Bsrc = B + (size_t)(bcol + srow) * K + ssw;

  char* lbase = (char*)&lds[0][0][0][0][0];
  const int woff = wave * 1024;

  f32x4 acc[8][4];
#pragma unroll
  for (int i = 0; i < 8; ++i)
#pragma unroll
    for (int j = 0; j < 4; ++j) acc[i][j] = (f32x4){0.f, 0.f, 0.f, 0.f};

  const int NT = K >> 6;

  // stage one 64-row quarter (1 glds, block-wide 8 KiB)
  auto SA = [&](int d, int h, int q, int tl) {
    __builtin_amdgcn_global_load_lds(
        (const g_void*)(Asrc + (size_t)(h * 128 + q * 64) * K + tl * 64),
        (lds_void*)(lbase + d * 32768 + h * 16384 + q * 8192 + woff), 16, 0, 0);
  };
  auto SB = [&](int d, int h, int q, int tl) {
    __builtin_amdgcn_global_load_lds(
        (const g_void*)(Bsrc + (size_t)(h * 128 + q * 64) * K + tl * 64),
        (lds_void*)(lbase + 65536 + d * 32768 + h * 16384 + q * 8192 + woff), 16, 0, 0);
  };

  auto LDA = [&](short8* a, int d, int mh, int ks) {
    const char* reg = lbase + d * 32768 + wm * 16384;
    const int ke = (ks * 32 + kg * 8) ^ ((lr & 7) << 3);
#pragma unroll
    for (int i = 0; i < 4; ++i) {
      const int row = (mh * 4 + i) * 16 + lr;
      a[i] = *(const short8*)(reg + row * 128 + ke * 2);
    }
  };
  auto LDB = [&](short8* b, int d, int ks) {
    const char* reg = lbase + 65536 + d * 32768 + (wn >> 1) * 16384;
    const int ke = (ks * 32 + kg * 8) ^ ((lr & 7) << 3);
#pragma unroll
    for (int n = 0; n < 4; ++n) {
      const int row = (wn & 1) * 64 + n * 16 + lr;
      b[n] = *(const short8*)(reg + row * 128 + ke * 2);
    }
  };

  auto MM = [&](int mh, short8* a, short8* b) {
    __builtin_amdgcn_s_setprio(1);
#pragma unroll
    for (int i = 0; i < 4; ++i)
#pragma unroll
      for (int n = 0; n < 4; ++n)
        acc[mh * 4 + i][n] = __builtin_amdgcn_mfma_f32_16x16x32_bf16(
            a[i], b[n], acc[mh * 4 + i][n], 0, 0, 0);
    __builtin_amdgcn_s_setprio(0);
  };

  // prologue: tile 0 full; tile 1 mimics steady-state p2/p3 issue order
  SA(0, 0, 0, 0); SA(0, 0, 1, 0); SA(0, 1, 0, 0); SA(0, 1, 1, 0);
  SB(0, 0, 0, 0); SB(0, 0, 1, 0); SB(0, 1, 0, 0); SB(0, 1, 1, 0);
  SB(1, 0, 0, 1); SB(1, 0, 1, 1); SA(1, 0, 0, 1);
  SB(1, 1, 0, 1); SB(1, 1, 1, 1); SA(1, 1, 0, 1);
  VMCNT6();
  BARRIER();

  short8 aT[4], bF0[4], bF1[4];
  for (int t = 0; t < NT; ++t) {
    const int buf = t & 1, nb = buf ^ 1;
    const int t1 = (t + 1 < NT) ? t + 1 : NT - 1;
    const int t2 = (t + 2 < NT) ? t + 2 : NT - 1;

    // p0: frags (mh0,ks0)+B(ks0); stage A(t+1) q1 quarters -> buf^1
    LDA(aT, buf, 0, 0); LDB(bF0, buf, 0);
    SA(nb, 0, 1, t1); SA(nb, 1, 1, t1);
    BARRIER(); MM(0, aT, bF0); BARRIER();

    // p1: frags (mh0,ks1)+B(ks1)
    LDA(aT, buf, 0, 1); LDB(bF1, buf, 1);
    BARRIER(); MM(0, aT, bF1); BARRIER();

    // p2: frags (mh1,ks0); stage B(t+2).h0 + A(t+2).h0q0 -> live buf
    LDA(aT, buf, 1, 0);
    SB(buf, 0, 0, t2); SB(buf, 0, 1, t2); SA(buf, 0, 0, t2);
    BARRIER(); MM(1, aT, bF0); BARRIER();

    // p3: frags (mh1,ks1); stage B(t+2).h1 + A(t+2).h1q0 -> live buf
    LDA(aT, buf, 1, 1);
    SB(buf, 1, 0, t2); SB(buf, 1, 1, t2); SA(buf, 1, 0, t2);
    BARRIER(); MM(1, aT, bF1);
    VMCNT6();
    BARRIER();
  }
  VMCNT0();

#pragma unroll
  for (int mi = 0; mi < 8; ++mi) {
#pragma unroll
    for (int ni = 0; ni < 4; ++ni) {
#pragma unroll
      for (int r = 0; r < 4; ++r) {
        const int row = brow + wm * 128 + mi * 16 + kg * 4 + r;
        const int col = bcol + wn * 64 + ni * 16 + lr;
        float v = acc[mi][ni][r] * scale;
        if (bias)  v += bias[col];
        if (resid) v += resid[(size_t)row * N + col];
        if (relu)  v = fmaxf(v, 0.0f);
        if (outF)  outF[(size_t)row * N + col] = v;
        if (outB)  outB[(size_t)row * N + col] = f2bf(v);
      }
    }
  }
}

// ---------------------------------------------------------------------------
// 256x128 8-phase GEMM (N=2048 GEMMs: grid (16,16) = 256 blocks, all CUs).
// 8 waves 4Mx2N, per-wave 64x64 (4x4 frags).  LDS: A[2][256][64] 64K +
// B[2][128][64] 32K = 96 KiB.  ALL ds_reads in p0/p1 (operands in regs by
// p1) => A(t+2) AND B(t+2) stage into live buf at p2/p3.  vmcnt(6)/tile.
// ---------------------------------------------------------------------------
__global__ __launch_bounds__(512, 2)
void gemm256x128_kernel(const unsigned short* __restrict__ A,
                        const unsigned short* __restrict__ B,
                        int M, int N, int K,
                        const float* __restrict__ bias,
                        const float* __restrict__ resid,
                        float scale, int relu,
                        float* __restrict__ outF,
                        unsigned short* __restrict__ outB)
{
  __shared__ __align__(16) unsigned short lds[49152];   // 96 KiB

  const int tid  = threadIdx.x;
  const int lane = tid & 63;
  const int wave = tid >> 6;     // 0..7
  const int wm   = wave >> 1;    // 0..3  (64-row strip)
  const int wn   = wave & 1;     // 0..1  (64-col strip)
  const int lr   = lane & 15;
  const int kg   = lane >> 4;
  const int brow = blockIdx.x * 256;
  const int bcol = blockIdx.y * 128;

  const int srow = tid >> 3;                              // 0..63
  const int ssw  = ((tid & 7) * 8) ^ ((srow & 7) << 3);
  const unsigned short* Asrc = A + (size_t)(brow + srow) * K + ssw;
  const unsigned short* Bsrc = B + (size_t)(bcol + srow) * K + ssw;

  char* lbase = (char*)&lds[0];
  const int woff = wave * 1024;

  f32x4 acc[4][4];
#pragma unroll
  for (int i = 0; i < 4; ++i)
#pragma unroll
    for (int j = 0; j < 4; ++j) acc[i][j] = (f32x4){0.f, 0.f, 0.f, 0.f};

  const int NT = K >> 6;

  // A: r = 64-row chunk 0..3 ; B: r = 0..1
  auto SA = [&](int d, int r, int tl) {
    __builtin_amdgcn_global_load_lds(
        (const g_void*)(Asrc + (size_t)(r * 64) * K + tl * 64),
        (lds_void*)(lbase + d * 32768 + r * 8192 + woff), 16, 0, 0);
  };
  auto SB = [&](int d, int r, int tl) {
    __builtin_amdgcn_global_load_lds(
        (const g_void*)(Bsrc + (size_t)(r * 64) * K + tl * 64),
        (lds_void*)(lbase + 65536 + d * 16384 + r * 8192 + woff), 16, 0, 0);
  };

  auto LDA = [&](short8* a, int d, int ks) {
    const char* reg = lbase + d * 32768;
    const int ke = (ks * 32 + kg * 8) ^ ((lr & 7) << 3);
#pragma unroll
    for (int mi = 0; mi < 4; ++mi) {
      const int row = wm * 64 + mi * 16 + lr;
      a[mi] = *(const short8*)(reg + row * 128 + ke * 2);
    }
  };
  auto LDB = [&](short8* b, int d, int ks) {
    const char* reg = lbase + 65536 + d * 16384;
    const int ke = (ks * 32 + kg * 8) ^ ((lr & 7) << 3);
#pragma unroll
    for (int n = 0; n < 4; ++n) {
      const int row = wn * 64 + n * 16 + lr;
      b[n] = *(const short8*)(reg + row * 128 + ke * 2);
    }
  };

  // 8 MFMA: mi in {mb, mb+1} x 4 N-frags
  auto MM = [&](int mb, short8* a, short8* b) {
    __builtin_amdgcn_s_setprio(1);
#pragma unroll
    for (int i = 0; i < 2; ++i)
#pragma unroll
      for (int n = 0; n < 4; ++n)
        acc[mb + i][n] = __builtin_amdgcn_mfma_f32_16x16x32_bf16(
            a[mb + i], b[n], acc[mb + i][n], 0, 0, 0);
    __builtin_amdgcn_s_setprio(0);
  };

  // prologue: tile 0 (6 glds), tile 1 in steady p2/p3 order (6 glds)
  SA(0, 0, 0); SA(0, 1, 0); SA(0, 2, 0); SA(0, 3, 0); SB(0, 0, 0); SB(0, 1, 0);
  SA(1, 0, 1); SA(1, 1, 1); SB(1, 0, 1);
  SA(1, 2, 1); SA(1, 3, 1); SB(1, 1, 1);
  VMCNT6();
  BARRIER();

  short8 aT0[4], aT1[4], bF0[4], bF1[4];
  for (int t = 0; t < NT; ++t) {
    const int buf = t & 1;
    const int t2 = (t + 2 < NT) ? t + 2 : NT - 1;

    // p0: all A(ks0) + all B(ks0)
    LDA(aT0, buf, 0); LDB(bF0, buf, 0);
    BARRIER(); MM(0, aT0, bF0); BARRIER();

    // p1: all A(ks1) + all B(ks1)
    LDA(aT1, buf, 1); LDB(bF1, buf, 1);
    BARRIER(); MM(0, aT1, bF1); BARRIER();

    // p2: stage t+2 (A r0,r1 + B r0) -> live buf (regions freed at p1)
    SA(buf, 0, t2); SA(buf, 1, t2); SB(buf, 0, t2);
    BARRIER(); MM(2, aT0, bF0); BARRIER();

    // p3: stage t+2 (A r2,r3 + B r1)
    SA(buf, 2, t2); SA(buf, 3, t2); SB(buf, 1, t2);
    BARRIER(); MM(2, aT1, bF1);
    VMCNT6();
    BARRIER();
  }
  VMCNT0();

#pragma unroll
  for (int mi = 0; mi < 4; ++mi) {
#pragma unroll
    for (int ni = 0; ni < 4; ++ni) {
#pragma unroll
      for (int r = 0; r < 4; ++r) {
        const int row = brow + wm * 64 + mi * 16 + kg * 4 + r;
        const int col = bcol + wn * 64 + ni * 16 + lr;
        float v = acc[mi][ni][r] * scale;
        if (bias)  v += bias[col];
        if (resid) v += resid[(size_t)row * N + col];
        if (relu)  v = fmaxf(v, 0.0f);
        if (outF)  outF[(size_t)row * N + col] = v;
        if (outB)  outB[(size_t)row * N + col] = f2bf(v);
      }
    }
  }
}

// ---------------------------------------------------------------------------
// row softmax: one block per row of [SEQ, SEQ] fp32 scores -> bf16 probs
// ---------------------------------------------------------------------------
__global__ __launch_bounds__(256) void softmax_kernel(
    const float* __restrict__ Sc, unsigned short* __restrict__ P) {
  __shared__ float buf[SEQ];
  __shared__ float redm[4];
  __shared__ float reds[4];
  const int tid = threadIdx.x;
  const int row = blockIdx.x;
  const float* src = Sc + (size_t)row * SEQ;

  float lmax = -3.0e38f;
  for (int i = tid * 4; i < SEQ; i += 1024) {
    float4 v = *(const float4*)(src + i);
    buf[i] = v.x; buf[i + 1] = v.y; buf[i + 2] = v.z; buf[i + 3] = v.w;
    lmax = fmaxf(lmax, fmaxf(fmaxf(v.x, v.y), fmaxf(v.z, v.w)));
  }
#pragma unroll
  for (int off = 32; off > 0; off >>= 1)
    lmax = fmaxf(lmax, __shfl_xor(lmax, off, 64));
  if ((tid & 63) == 0) redm[tid >> 6] = lmax;
  __syncthreads();
  const float m = fmaxf(fmaxf(redm[0], redm[1]), fmaxf(redm[2], redm[3]));

  float lsum = 0.0f;
  for (int i = tid; i < SEQ; i += 256) {
    float e = __expf(buf[i] - m);
    buf[i] = e;
    lsum += e;
  }
#pragma unroll
  for (int off = 32; off > 0; off >>= 1)
    lsum += __shfl_xor(lsum, off, 64);
  if ((tid & 63) == 0) reds[tid >> 6] = lsum;
  __syncthreads();
  const float inv = 1.0f / (reds[0] + reds[1] + reds[2] + reds[3]);

  unsigned short* dst = P + (size_t)row * SEQ;
  for (int i = tid; i < SEQ; i += 256) dst[i] = f2bf(buf[i] * inv);
}

// ---------------------------------------------------------------------------
// launch
// ---------------------------------------------------------------------------
extern "C" void kernel_launch(void* const* d_in, const int* in_sizes, int n_in,
                              void* d_out, int out_size, void* d_ws, size_t ws_size,
                              hipStream_t stream) {
  const float* x  = (const float*)d_in[0];
  const float* qw = (const float*)d_in[1];
  const float* qb = (const float*)d_in[2];
  const float* kw = (const float*)d_in[3];
  const float* kb = (const float*)d_in[4];
  const float* vw = (const float*)d_in[5];
  const float* vb = (const float*)d_in[6];
  const float* w1 = (const float*)d_in[7];
  const float* b1 = (const float*)d_in[8];
  const float* w2 = (const float*)d_in[9];
  const float* b2 = (const float*)d_in[10];
  float* out = (float*)d_out;   // [hidden(8388608) | k(2097152) | v(8388608)]
  char* ws = (char*)d_ws;

  const size_t MB = 1048576;
  unsigned short* Xb   = (unsigned short*)(ws + 0 * MB);
  unsigned short* VWb  = (unsigned short*)(ws + 16 * MB);
  unsigned short* QKWb = (unsigned short*)(ws + 24 * MB);
  unsigned short* Pb   = (unsigned short*)(ws + 0 * MB);     // overlays Xb/VWb/QKWb
  unsigned short* W1b  = (unsigned short*)(ws + 32 * MB);
  unsigned short* W2b  = (unsigned short*)(ws + 40 * MB);
  unsigned short* Qb   = (unsigned short*)(ws + 48 * MB);
  unsigned short* Kb   = (unsigned short*)(ws + 52 * MB);
  unsigned short* Vb   = (unsigned short*)(ws + 56 * MB);
  unsigned short* VTb  = (unsigned short*)(ws + 72 * MB);
  float*          Sc   = (float*)(ws + 88 * MB);
  float*          XR   = (float*)(ws + 88 * MB);             // overlays dead Sc
  unsigned short* X1b  = (unsigned short*)(ws + 120 * MB);   // overlays dead Sc
  unsigned short* XRb  = (unsigned short*)(ws + 136 * MB);   // overlays dead Sc

  // casts to bf16 (QKWb = [qw ; kw] rows concatenated)
  cast_bf16_kernel<<<8192, 256, 0, stream>>>(x,  Xb,  2097152);
  cast_bf16_kernel<<<1024, 256, 0, stream>>>(qw, QKWb, 262144);
  cast_bf16_kernel<<<1024, 256, 0, stream>>>(kw, QKWb + 512 * 2048, 262144);
  cast_bf16_kernel<<<4096, 256, 0, stream>>>(vw, VWb, 1048576);
  cast_bf16_kernel<<<4096, 256, 0, stream>>>(w1, W1b, 1048576);
  cast_bf16_kernel<<<4096, 256, 0, stream>>>(w2, W2b, 1048576);

  // q,k = x @ [qw;kw]^T + [qb;kb]   (fused, split epilogue; 2-phase kernel)
  gemm_bt_kernel<<<dim3(32, 8), dim3(256), 0, stream>>>(
      Xb, QKWb, SEQ, 1024, DMODEL, 512, qb, kb, nullptr, 1.0f, 0,
      nullptr, Qb, out + 8388608, Kb);
  // v = x @ vw^T + vb   -> fp32 (out) + bf16
  gemm256x128_kernel<<<dim3(16, 16), dim3(512), 0, stream>>>(
      Xb, VWb, SEQ, DMODEL, DMODEL, vb, nullptr, 1.0f, 0,
      out + 10485760, Vb);
  // VTb = Vb^T  ([2048][4096])
  transpose_bf16_kernel<<<dim3(64, 32), dim3(256), 0, stream>>>(Vb, VTb, SEQ, DMODEL);
  // scores = (q @ k^T) / sqrt(512)  -> fp32
  gemm256_kernel<<<dim3(16, 16), dim3(512), 0, stream>>>(
      Qb, Kb, SEQ, SEQ, DINT, nullptr, nullptr,
      0.04419417382415922f, 0, Sc, nullptr);
  // P = softmax(scores)  -> bf16
  softmax_kernel<<<4096, dim3(256), 0, stream>>>(Sc, Pb);
  // x_residual = P @ V + x  -> fp32 + bf16
  gemm256x128_kernel<<<dim3(16, 16), dim3(512), 0, stream>>>(
      Pb, VTb, SEQ, DMODEL, SEQ, nullptr, x, 1.0f, 0, XR, XRb);
  // x1 = relu(x_residual @ w1^T + b1)  -> bf16
  gemm256x128_kernel<<<dim3(16, 16), dim3(512), 0, stream>>>(
      XRb, W1b, SEQ, DMODEL, DMODEL, b1, nullptr, 1.0f, 1, nullptr, X1b);
  // hidden = x1 @ w2^T + b2 + x_residual  -> fp32 (out)
  gemm256x128_kernel<<<dim3(16, 16), dim3(512), 0, stream>>>(
      X1b, W2b, SEQ, DMODEL, DMODEL, b2, XR, 1.0f, 0, out, nullptr);
}

// Round 7
// 390.531 us; speedup vs baseline: 1.3408x; 1.0164x over previous
//
#include <hip/hip_runtime.h>
#include <cstdint>
#include <cstddef>

// ---------------------------------------------------------------------------
// TransformerLayer: hidden,k,v = f(x, qw,qb, kw,kb, vw,vb, w1,b1, w2,b2)
// S=4096, D_MODEL=2048, D_INT=512.  bf16 MFMA GEMMs, fp32 accumulate.
// Round 7: fix round-6 race.  gemm256x128 = reg-double-buffered pipeline
// with the safe ordering per tile: vmcnt(0) -> barrier -> STAGE(t+2) ->
// RD(t+1) -> MFMA(t) -> lgkmcnt(0).  (drain BEFORE barrier: vmcnt proves
// only own-wave loads landed; the barrier extends it to all waves.)
// ---------------------------------------------------------------------------

typedef __attribute__((ext_vector_type(8))) short short8;   // 8 x bf16 bits
typedef __attribute__((ext_vector_type(4))) float f32x4;    // MFMA accum

typedef __attribute__((address_space(3))) void lds_void;
typedef __attribute__((address_space(1))) void g_void;

#define SEQ    4096
#define DMODEL 2048
#define DINT   512

#define MEMF() asm volatile("" ::: "memory")
#define BARRIER() do { MEMF(); __builtin_amdgcn_s_barrier(); MEMF(); } while (0)
#define VMCNT6() asm volatile("s_waitcnt vmcnt(6)" ::: "memory")
#define VMCNT0() asm volatile("s_waitcnt vmcnt(0)" ::: "memory")
#define LGKM0()  asm volatile("s_waitcnt lgkmcnt(0)" ::: "memory")

// fp32 -> bf16 bits, round-to-nearest-even
__device__ __forceinline__ unsigned short f2bf(float f) {
  union { float f; unsigned int u; } a;
  a.f = f;
  unsigned int u = a.u;
  u += 0x7fffu + ((u >> 16) & 1u);
  return (unsigned short)(u >> 16);
}

// ---------------------------------------------------------------------------
// cast: fp32 -> bf16 (4 elems / thread)
// ---------------------------------------------------------------------------
__global__ __launch_bounds__(256) void cast_bf16_kernel(
    const float* __restrict__ in, unsigned short* __restrict__ out, int n4) {
  int i = blockIdx.x * 256 + threadIdx.x;
  if (i >= n4) return;
  float4 v = ((const float4*)in)[i];
  ushort4 o;
  o.x = f2bf(v.x); o.y = f2bf(v.y); o.z = f2bf(v.z); o.w = f2bf(v.w);
  ((ushort4*)out)[i] = o;
}

// ---------------------------------------------------------------------------
// bf16 transpose: out[C][R] = in[R][C].  64x64 LDS tile.
// ---------------------------------------------------------------------------
__global__ __launch_bounds__(256) void transpose_bf16_kernel(
    const unsigned short* __restrict__ in, unsigned short* __restrict__ out,
    int R, int C) {
  __shared__ unsigned short tile[64][65];
  const int tx = threadIdx.x & 63;
  const int ty = threadIdx.x >> 6;
  const int r0 = blockIdx.x * 64;
  const int c0 = blockIdx.y * 64;
#pragma unroll
  for (int i = 0; i < 64; i += 4)
    tile[ty + i][tx] = in[(size_t)(r0 + ty + i) * C + c0 + tx];
  __syncthreads();
#pragma unroll
  for (int i = 0; i < 64; i += 4)
    out[(size_t)(c0 + ty + i) * R + r0 + tx] = tile[tx][ty + i];
}

// ---------------------------------------------------------------------------
// 2-phase 128^2 GEMM, kept for the QK fused GEMM (N=1024, grid 32x8 = 256).
// ---------------------------------------------------------------------------
#define BM 128
#define BN 128
#define BK 64

__global__ __launch_bounds__(256)
void gemm_bt_kernel(const unsigned short* __restrict__ A,
                    const unsigned short* __restrict__ B,
                    int M, int N, int K, int split,
                    const float* __restrict__ biasA,
                    const float* __restrict__ biasB,
                    const float* __restrict__ resid,
                    float scale, int relu,
                    float* __restrict__ outFA,
                    unsigned short* __restrict__ outBA,
                    float* __restrict__ outFB,
                    unsigned short* __restrict__ outBB)
{
  __shared__ __align__(16) unsigned short As[2][BM][BK];
  __shared__ __align__(16) unsigned short Bs[2][BN][BK];

  const int tid  = threadIdx.x;
  const int lane = tid & 63;
  const int wave = tid >> 6;
  const int wr   = wave >> 1;
  const int wc   = wave & 1;
  const int brow = blockIdx.x * BM;
  const int bcol = blockIdx.y * BN;
  const int lr   = lane & 15;
  const int kg   = lane >> 4;

  const int srow  = tid >> 3;
  const int scol  = (tid & 7) * 8;
  const int wbase = wave * 8;
  const unsigned short* Ab = A + (size_t)(brow + srow) * K + scol;
  const unsigned short* Bb = B + (size_t)(bcol + srow) * K + scol;

  f32x4 acc[4][4];
#pragma unroll
  for (int i = 0; i < 4; i++)
#pragma unroll
    for (int j = 0; j < 4; j++) acc[i][j] = (f32x4){0.f, 0.f, 0.f, 0.f};

  auto stage = [&](int d, int k0) {
#pragma unroll
    for (int j = 0; j < 4; ++j) {
      __builtin_amdgcn_global_load_lds((const g_void*)(Ab + (size_t)(j * 32) * K + k0),
                                       (lds_void*)&As[d][j * 32 + wbase][0], 16, 0, 0);
      __builtin_amdgcn_global_load_lds((const g_void*)(Bb + (size_t)(j * 32) * K + k0),
                                       (lds_void*)&Bs[d][j * 32 + wbase][0], 16, 0, 0);
    }
  };

  auto compute = [&](int d) {
    short8 aF[4][2], bF[4][2];
#pragma unroll
    for (int mi = 0; mi < 4; ++mi)
#pragma unroll
      for (int ks = 0; ks < 2; ++ks)
        aF[mi][ks] = *(const short8*)&As[d][wr * 64 + mi * 16 + lr][ks * 32 + kg * 8];
#pragma unroll
    for (int ni = 0; ni < 4; ++ni)
#pragma unroll
      for (int ks = 0; ks < 2; ++ks)
        bF[ni][ks] = *(const short8*)&Bs[d][wc * 64 + ni * 16 + lr][ks * 32 + kg * 8];
#pragma unroll
    for (int ks = 0; ks < 2; ++ks)
#pragma unroll
      for (int mi = 0; mi < 4; ++mi)
#pragma unroll
        for (int ni = 0; ni < 4; ++ni)
          acc[mi][ni] = __builtin_amdgcn_mfma_f32_16x16x32_bf16(
              aF[mi][ks], bF[ni][ks], acc[mi][ni], 0, 0, 0);
  };

  stage(0, 0);
  __syncthreads();
  int c = 0;
  const int NT = K >> 6;
  for (int t = 0; t < NT; ++t) {
    if (t + 1 < NT) stage(c ^ 1, (t + 1) << 6);
    compute(c);
    __syncthreads();
    c ^= 1;
  }

  const int wB = N - split;
#pragma unroll
  for (int mi = 0; mi < 4; mi++) {
#pragma unroll
    for (int ni = 0; ni < 4; ni++) {
#pragma unroll
      for (int r = 0; r < 4; r++) {
        const int row = brow + wr * 64 + mi * 16 + kg * 4 + r;
        const int col = bcol + wc * 64 + ni * 16 + lr;
        float v = acc[mi][ni][r] * scale;
        if (col < split) {
          if (biasA) v += biasA[col];
          if (resid) v += resid[(size_t)row * N + col];
          if (relu)  v = fmaxf(v, 0.0f);
          if (outFA) outFA[(size_t)row * split + col] = v;
          if (outBA) outBA[(size_t)row * split + col] = f2bf(v);
        } else {
          const int c2 = col - split;
          if (biasB) v += biasB[c2];
          if (outFB) outFB[(size_t)row * wB + c2] = v;
          if (outBB) outBB[(size_t)row * wB + c2] = f2bf(v);
        }
      }
    }
  }
}

// ---------------------------------------------------------------------------
// 256^2 8-phase GEMM, m201 deep schedule (scores GEMM: grid (16,16)).
// (unchanged from round 5 -- passed correctness there)
// ---------------------------------------------------------------------------
__global__ __launch_bounds__(512, 2)
void gemm256_kernel(const unsigned short* __restrict__ A,
                    const unsigned short* __restrict__ B,
                    int M, int N, int K,
                    const float* __restrict__ bias,
                    const float* __restrict__ resid,
                    float scale, int relu,
                    float* __restrict__ outF,
                    unsigned short* __restrict__ outB)
{
  __shared__ __align__(16) unsigned short lds[2][2][2][128][64];  // 128 KiB

  const int tid  = threadIdx.x;
  const int lane = tid & 63;
  const int wave = tid >> 6;     // 0..7
  const int wm   = wave >> 2;    // 0..1  (128-row half)
  const int wn   = wave & 3;     // 0..3  (64-col strip)
  const int lr   = lane & 15;
  const int kg   = lane >> 4;
  const int brow = blockIdx.x * 256;
  const int bcol = blockIdx.y * 256;

  const int srow = tid >> 3;                              // 0..63
  const int ssw  = ((tid & 7) * 8) ^ ((srow & 7) << 3);   // pre-swizzled k
  const unsigned short* Asrc = A + (size_t)(brow + srow) * K + ssw;
  const unsigned short* Bsrc = B + (size_t)(bcol + srow) * K + ssw;

  char* lbase = (char*)&lds[0][0][0][0][0];
  const int woff = wave * 1024;

  f32x4 acc[8][4];
#pragma unroll
  for (int i = 0; i < 8; ++i)
#pragma unroll
    for (int j = 0; j < 4; ++j) acc[i][j] = (f32x4){0.f, 0.f, 0.f, 0.f};

  const int NT = K >> 6;

  auto SA = [&](int d, int h, int q, int tl) {
    __builtin_amdgcn_global_load_lds(
        (const g_void*)(Asrc + (size_t)(h * 128 + q * 64) * K + tl * 64),
        (lds_void*)(lbase + d * 32768 + h * 16384 + q * 8192 + woff), 16, 0, 0);
  };
  auto SB = [&](int d, int h, int q, int tl) {
    __builtin_amdgcn_global_load_lds(
        (const g_void*)(Bsrc + (size_t)(h * 128 + q * 64) * K + tl * 64),
        (lds_void*)(lbase + 65536 + d * 32768 + h * 16384 + q * 8192 + woff), 16, 0, 0);
  };

  auto LDA = [&](short8* a, int d, int mh, int ks) {
    const char* reg = lbase + d * 32768 + wm * 16384;
    const int ke = (ks * 32 + kg * 8) ^ ((lr & 7) << 3);
#pragma unroll
    for (int i = 0; i < 4; ++i) {
      const int row = (mh * 4 + i) * 16 + lr;
      a[i] = *(const short8*)(reg + row * 128 + ke * 2);
    }
  };
  auto LDB = [&](short8* b, int d, int ks) {
    const char* reg = lbase + 65536 + d * 32768 + (wn >> 1) * 16384;
    const int ke = (ks * 32 + kg * 8) ^ ((lr & 7) << 3);
#pragma unroll
    for (int n = 0; n < 4; ++n) {
      const int row = (wn & 1) * 64 + n * 16 + lr;
      b[n] = *(const short8*)(reg + row * 128 + ke * 2);
    }
  };

  auto MM = [&](int mh, short8* a, short8* b) {
    __builtin_amdgcn_s_setprio(1);
#pragma unroll
    for (int i = 0; i < 4; ++i)
#pragma unroll
      for (int n = 0; n < 4; ++n)
        acc[mh * 4 + i][n] = __builtin_amdgcn_mfma_f32_16x16x32_bf16(
            a[i], b[n], acc[mh * 4 + i][n], 0, 0, 0);
    __builtin_amdgcn_s_setprio(0);
  };

  SA(0, 0, 0, 0); SA(0, 0, 1, 0); SA(0, 1, 0, 0); SA(0, 1, 1, 0);
  SB(0, 0, 0, 0); SB(0, 0, 1, 0); SB(0, 1, 0, 0); SB(0, 1, 1, 0);
  SB(1, 0, 0, 1); SB(1, 0, 1, 1); SA(1, 0, 0, 1);
  SB(1, 1, 0, 1); SB(1, 1, 1, 1); SA(1, 1, 0, 1);
  VMCNT6();
  BARRIER();

  short8 aT[4], bF0[4], bF1[4];
  for (int t = 0; t < NT; ++t) {
    const int buf = t & 1, nb = buf ^ 1;
    const int t1 = (t + 1 < NT) ? t + 1 : NT - 1;
    const int t2 = (t + 2 < NT) ? t + 2 : NT - 1;

    LDA(aT, buf, 0, 0); LDB(bF0, buf, 0);
    SA(nb, 0, 1, t1); SA(nb, 1, 1, t1);
    BARRIER(); MM(0, aT, bF0); BARRIER();

    LDA(aT, buf, 0, 1); LDB(bF1, buf, 1);
    BARRIER(); MM(0, aT, bF1); BARRIER();

    LDA(aT, buf, 1, 0);
    SB(buf, 0, 0, t2); SB(buf, 0, 1, t2); SA(buf, 0, 0, t2);
    BARRIER(); MM(1, aT, bF0); BARRIER();

    LDA(aT, buf, 1, 1);
    SB(buf, 1, 0, t2); SB(buf, 1, 1, t2); SA(buf, 1, 0, t2);
    BARRIER(); MM(1, aT, bF1);
    VMCNT6();
    BARRIER();
  }
  VMCNT0();

#pragma unroll
  for (int mi = 0; mi < 8; ++mi) {
#pragma unroll
    for (int ni = 0; ni < 4; ++ni) {
#pragma unroll
      for (int r = 0; r < 4; ++r) {
        const int row = brow + wm * 128 + mi * 16 + kg * 4 + r;
        const int col = bcol + wn * 64 + ni * 16 + lr;
        float v = acc[mi][ni][r] * scale;
        if (bias)  v += bias[col];
        if (resid) v += resid[(size_t)row * N + col];
        if (relu)  v = fmaxf(v, 0.0f);
        if (outF)  outF[(size_t)row * N + col] = v;
        if (outB)  outB[(size_t)row * N + col] = f2bf(v);
      }
    }
  }
}

// ---------------------------------------------------------------------------
// 256x128 reg-double-buffered GEMM (grid (16,16) = 256 blocks).
// 8 waves 4Mx2N, per-wave 64x64.  LDS: A[2][256][64] 64K + B[2][128][64] 32K.
// ONE barrier per K-tile.  Per sub-iter (computes tile t):
//   VMCNT0()      own staging loads (issued last sub-iter, tile t+1) landed
//   BARRIER       => ALL waves' tile-t+1 loads landed; ALL waves' LDS reads
//                    of tile t retired (lgkmcnt(0) before this barrier)
//   STAGE(t+2) -> buf(t&1)   overwrite tile t's freed buffer
//   RD(t+1)    -> other reg set  (16 ds_read_b128; overlap MFMA below)
//   MMALL(t)   on current reg set (32 MFMA)
//   LGKM0()    reads retired (WAR invariant for next barrier)
// Staging loads get a full sub-iter (~LDS-pipe-bound, >HBM latency) of cover
// before their drain, so VMCNT0 is cheap in steady state.
// ---------------------------------------------------------------------------
__global__ __launch_bounds__(512, 2)
void gemm256x128_kernel(const unsigned short* __restrict__ A,
                        const unsigned short* __restrict__ B,
                        int M, int N, int K,
                        const float* __restrict__ bias,
                        const float* __restrict__ resid,
                        float scale, int relu,
                        float* __restrict__ outF,
                        unsigned short* __restrict__ outB)
{
  __shared__ __align__(16) unsigned short lds[49152];   // 96 KiB

  const int tid  = threadIdx.x;
  const int lane = tid & 63;
  const int wave = tid >> 6;     // 0..7
  const int wm   = wave >> 1;    // 0..3  (64-row strip)
  const int wn   = wave & 1;     // 0..1  (64-col strip)
  const int lr   = lane & 15;
  const int kg   = lane >> 4;
  const int brow = blockIdx.x * 256;
  const int bcol = blockIdx.y * 128;

  const int srow = tid >> 3;                              // 0..63
  const int ssw  = ((tid & 7) * 8) ^ ((srow & 7) << 3);
  const unsigned short* Asrc = A + (size_t)(brow + srow) * K + ssw;
  const unsigned short* Bsrc = B + (size_t)(bcol + srow) * K + ssw;

  char* lbase = (char*)&lds[0];
  const int woff = wave * 1024;

  f32x4 acc[4][4];
#pragma unroll
  for (int i = 0; i < 4; ++i)
#pragma unroll
    for (int j = 0; j < 4; ++j) acc[i][j] = (f32x4){0.f, 0.f, 0.f, 0.f};

  const int NT = K >> 6;   // even for all call sites (K = 2048 / 4096)

  // stage tile tl into dbuf d: A rows 0..255 (4 chunks) + B rows 0..127 (2)
  auto STAGE = [&](int d, int tl) {
#pragma unroll
    for (int r = 0; r < 4; ++r)
      __builtin_amdgcn_global_load_lds(
          (const g_void*)(Asrc + (size_t)(r * 64) * K + tl * 64),
          (lds_void*)(lbase + d * 32768 + r * 8192 + woff), 16, 0, 0);
#pragma unroll
    for (int r = 0; r < 2; ++r)
      __builtin_amdgcn_global_load_lds(
          (const g_void*)(Bsrc + (size_t)(r * 64) * K + tl * 64),
          (lds_void*)(lbase + 65536 + d * 16384 + r * 8192 + woff), 16, 0, 0);
  };

  // read ALL frags of one tile: a[ks*4+mi], b[ks*4+n]
  auto RD = [&](short8* a, short8* b, int d) {
#pragma unroll
    for (int ks = 0; ks < 2; ++ks) {
      const int ke = (ks * 32 + kg * 8) ^ ((lr & 7) << 3);
      const char* ra = lbase + d * 32768;
      const char* rb = lbase + 65536 + d * 16384;
#pragma unroll
      for (int mi = 0; mi < 4; ++mi)
        a[ks * 4 + mi] = *(const short8*)(ra + (wm * 64 + mi * 16 + lr) * 128 + ke * 2);
#pragma unroll
      for (int n = 0; n < 4; ++n)
        b[ks * 4 + n] = *(const short8*)(rb + (wn * 64 + n * 16 + lr) * 128 + ke * 2);
    }
  };

  auto MMALL = [&](short8* a, short8* b) {
    __builtin_amdgcn_s_setprio(1);
#pragma unroll
    for (int ks = 0; ks < 2; ++ks)
#pragma unroll
      for (int mi = 0; mi < 4; ++mi)
#pragma unroll
        for (int n = 0; n < 4; ++n)
          acc[mi][n] = __builtin_amdgcn_mfma_f32_16x16x32_bf16(
              a[ks * 4 + mi], b[ks * 4 + n], acc[mi][n], 0, 0, 0);
    __builtin_amdgcn_s_setprio(0);
  };

  // prologue: tiles 0,1 staged & drained; tile0 -> E regs
  STAGE(0, 0);
  STAGE(1, 1);
  VMCNT0();
  BARRIER();
  short8 aE[8], bE[8], aO[8], bO[8];
  RD(aE, bE, 0);
  LGKM0();

  for (int t = 0; t < NT; t += 2) {
    // even sub-iter: compute tile t (E regs); read t+1 -> O; stage t+2 -> buf0
    VMCNT0();
    BARRIER();
    { const int t2 = (t + 2 < NT) ? t + 2 : NT - 1; STAGE(0, t2); }
    RD(aO, bO, 1);
    MMALL(aE, bE);
    LGKM0();
    // odd sub-iter: compute tile t+1 (O regs); read t+2 -> E; stage t+3 -> buf1
    VMCNT0();
    BARRIER();
    { const int t3 = (t + 3 < NT) ? t + 3 : NT - 1; STAGE(1, t3); }
    RD(aE, bE, 0);
    MMALL(aO, bO);
    LGKM0();
  }
  VMCNT0();

#pragma unroll
  for (int mi = 0; mi < 4; ++mi) {
#pragma unroll
    for (int ni = 0; ni < 4; ++ni) {
#pragma unroll
      for (int r = 0; r < 4; ++r) {
        const int row = brow + wm * 64 + mi * 16 + kg * 4 + r;
        const int col = bcol + wn * 64 + ni * 16 + lr;
        float v = acc[mi][ni][r] * scale;
        if (bias)  v += bias[col];
        if (resid) v += resid[(size_t)row * N + col];
        if (relu)  v = fmaxf(v, 0.0f);
        if (outF)  outF[(size_t)row * N + col] = v;
        if (outB)  outB[(size_t)row * N + col] = f2bf(v);
      }
    }
  }
}

// ---------------------------------------------------------------------------
// row softmax: one block per row of [SEQ, SEQ] fp32 scores -> bf16 probs
// ---------------------------------------------------------------------------
__global__ __launch_bounds__(256) void softmax_kernel(
    const float* __restrict__ Sc, unsigned short* __restrict__ P) {
  __shared__ float buf[SEQ];
  __shared__ float redm[4];
  __shared__ float reds[4];
  const int tid = threadIdx.x;
  const int row = blockIdx.x;
  const float* src = Sc + (size_t)row * SEQ;

  float lmax = -3.0e38f;
  for (int i = tid * 4; i < SEQ; i += 1024) {
    float4 v = *(const float4*)(src + i);
    buf[i] = v.x; buf[i + 1] = v.y; buf[i + 2] = v.z; buf[i + 3] = v.w;
    lmax = fmaxf(lmax, fmaxf(fmaxf(v.x, v.y), fmaxf(v.z, v.w)));
  }
#pragma unroll
  for (int off = 32; off > 0; off >>= 1)
    lmax = fmaxf(lmax, __shfl_xor(lmax, off, 64));
  if ((tid & 63) == 0) redm[tid >> 6] = lmax;
  __syncthreads();
  const float m = fmaxf(fmaxf(redm[0], redm[1]), fmaxf(redm[2], redm[3]));

  float lsum = 0.0f;
  for (int i = tid; i < SEQ; i += 256) {
    float e = __expf(buf[i] - m);
    buf[i] = e;
    lsum += e;
  }
#pragma unroll
  for (int off = 32; off > 0; off >>= 1)
    lsum += __shfl_xor(lsum, off, 64);
  if ((tid & 63) == 0) reds[tid >> 6] = lsum;
  __syncthreads();
  const float inv = 1.0f / (reds[0] + reds[1] + reds[2] + reds[3]);

  unsigned short* dst = P + (size_t)row * SEQ;
  for (int i = tid; i < SEQ; i += 256) dst[i] = f2bf(buf[i] * inv);
}

// ---------------------------------------------------------------------------
// launch
// ---------------------------------------------------------------------------
extern "C" void kernel_launch(void* const* d_in, const int* in_sizes, int n_in,
                              void* d_out, int out_size, void* d_ws, size_t ws_size,
                              hipStream_t stream) {
  const float* x  = (const float*)d_in[0];
  const float* qw = (const float*)d_in[1];
  const float* qb = (const float*)d_in[2];
  const float* kw = (const float*)d_in[3];
  const float* kb = (const float*)d_in[4];
  const float* vw = (const float*)d_in[5];
  const float* vb = (const float*)d_in[6];
  const float* w1 = (const float*)d_in[7];
  const float* b1 = (const float*)d_in[8];
  const float* w2 = (const float*)d_in[9];
  const float* b2 = (const float*)d_in[10];
  float* out = (float*)d_out;   // [hidden(8388608) | k(2097152) | v(8388608)]
  char* ws = (char*)d_ws;

  const size_t MB = 1048576;
  unsigned short* Xb   = (unsigned short*)(ws + 0 * MB);
  unsigned short* VWb  = (unsigned short*)(ws + 16 * MB);
  unsigned short* QKWb = (unsigned short*)(ws + 24 * MB);
  unsigned short* Pb   = (unsigned short*)(ws + 0 * MB);     // overlays Xb/VWb/QKWb
  unsigned short* W1b  = (unsigned short*)(ws + 32 * MB);
  unsigned short* W2b  = (unsigned short*)(ws + 40 * MB);
  unsigned short* Qb   = (unsigned short*)(ws + 48 * MB);
  unsigned short* Kb   = (unsigned short*)(ws + 52 * MB);
  unsigned short* Vb   = (unsigned short*)(ws + 56 * MB);
  unsigned short* VTb  = (unsigned short*)(ws + 72 * MB);
  float*          Sc   = (float*)(ws + 88 * MB);
  float*          XR   = (float*)(ws + 88 * MB);             // overlays dead Sc
  unsigned short* X1b  = (unsigned short*)(ws + 120 * MB);   // overlays dead Sc
  unsigned short* XRb  = (unsigned short*)(ws + 136 * MB);   // overlays dead Sc

  // casts to bf16 (QKWb = [qw ; kw] rows concatenated)
  cast_bf16_kernel<<<8192, 256, 0, stream>>>(x,  Xb,  2097152);
  cast_bf16_kernel<<<1024, 256, 0, stream>>>(qw, QKWb, 262144);
  cast_bf16_kernel<<<1024, 256, 0, stream>>>(kw, QKWb + 512 * 2048, 262144);
  cast_bf16_kernel<<<4096, 256, 0, stream>>>(vw, VWb, 1048576);
  cast_bf16_kernel<<<4096, 256, 0, stream>>>(w1, W1b, 1048576);
  cast_bf16_kernel<<<4096, 256, 0, stream>>>(w2, W2b, 1048576);

  // q,k = x @ [qw;kw]^T + [qb;kb]   (fused, split epilogue; 2-phase kernel)
  gemm_bt_kernel<<<dim3(32, 8), dim3(256), 0, stream>>>(
      Xb, QKWb, SEQ, 1024, DMODEL, 512, qb, kb, nullptr, 1.0f, 0,
      nullptr, Qb, out + 8388608, Kb);
  // v = x @ vw^T + vb   -> fp32 (out) + bf16
  gemm256x128_kernel<<<dim3(16, 16), dim3(512), 0, stream>>>(
      Xb, VWb, SEQ, DMODEL, DMODEL, vb, nullptr, 1.0f, 0,
      out + 10485760, Vb);
  // VTb = Vb^T  ([2048][4096])
  transpose_bf16_kernel<<<dim3(64, 32), dim3(256), 0, stream>>>(Vb, VTb, SEQ, DMODEL);
  // scores = (q @ k^T) / sqrt(512)  -> fp32
  gemm256_kernel<<<dim3(16, 16), dim3(512), 0, stream>>>(
      Qb, Kb, SEQ, SEQ, DINT, nullptr, nullptr,
      0.04419417382415922f, 0, Sc, nullptr);
  // P = softmax(scores)  -> bf16
  softmax_kernel<<<4096, dim3(256), 0, stream>>>(Sc, Pb);
  // x_residual = P @ V + x  -> fp32 + bf16
  gemm256x128_kernel<<<dim3(16, 16), dim3(512), 0, stream>>>(
      Pb, VTb, SEQ, DMODEL, SEQ, nullptr, x, 1.0f, 0, XR, XRb);
  // x1 = relu(x_residual @ w1^T + b1)  -> bf16
  gemm256x128_kernel<<<dim3(16, 16), dim3(512), 0, stream>>>(
      XRb, W1b, SEQ, DMODEL, DMODEL, b1, nullptr, 1.0f, 1, nullptr, X1b);
  // hidden = x1 @ w2^T + b2 + x_residual  -> fp32 (out)
  gemm256x128_kernel<<<dim3(16, 16), dim3(512), 0, stream>>>(
      X1b, W2b, SEQ, DMODEL, DMODEL, b2, XR, 1.0f, 0, out, nullptr);
}